// Round 1
// baseline (98.109 us; speedup 1.0000x reference)
//
#include <hip/hip_runtime.h>
#include <math.h>

// Problem constants (match reference)
#define HH    13
#define WW    1024
#define BATCH 256
#define C1    16
#define C2    32
#define PH    6      // pooled h1 rows   (13 -> floor 6)
#define PW    512    // pooled h1 cols   (1024 -> 512)
#define P2H   3      // pooled h2 rows   (6 -> 3)
#define P2W   256    // pooled h2 cols   (512 -> 256)
#define FLAT  (C2 * P2H * P2W)   // 24576
#define NFC1  128
#define CW    64     // chunk width in pooled-h1 column space

// ---------------------------------------------------------------------------
// Kernel 1: per-sample Shannon entropy of normalized |x|, threshold -> mask.
// ent = log(S) - T/S  with S = sum(a), T = sum(a*log a), a = |x| + 1e-10.
// ---------------------------------------------------------------------------
__global__ __launch_bounds__(256) void entropy_kernel(const float* __restrict__ x,
                                                      float* __restrict__ mask) {
    const int b = blockIdx.x;
    const float* xb = x + (size_t)b * (HH * WW);
    float s = 0.f, t = 0.f;
    for (int i = threadIdx.x; i < HH * WW; i += 256) {
        float a = fabsf(xb[i]) + 1e-10f;
        s += a;
        t += a * __logf(a);
    }
    // wave (64-lane) reduction
    for (int off = 32; off >= 1; off >>= 1) {
        s += __shfl_down(s, off);
        t += __shfl_down(t, off);
    }
    __shared__ float ss[4], tt[4];
    const int wave = threadIdx.x >> 6;
    const int lane = threadIdx.x & 63;
    if (lane == 0) { ss[wave] = s; tt[wave] = t; }
    __syncthreads();
    if (threadIdx.x == 0) {
        const float S = ss[0] + ss[1] + ss[2] + ss[3];
        const float T = tt[0] + tt[1] + tt[2] + tt[3];
        const float ent = __logf(S) - T / S;
        mask[b] = (ent < 2.0f) ? 1.0f : 0.0f;
    }
}

// ---------------------------------------------------------------------------
// Kernel 2: full network per sample, gated by mask.
// out[b] = mask[b] * f(x_b); when mask==0, f need not be evaluated (exact).
// Full path: conv1(3x3,SAME)+relu+pool2 -> conv2(3x3,SAME)+relu+pool2
//            -> fc1(24576->128)+relu -> fc2(128->2), all fp32, LDS-chunked.
// ---------------------------------------------------------------------------
__global__ __launch_bounds__(256) void cnn_kernel(
    const float* __restrict__ x,
    const float* __restrict__ w1, const float* __restrict__ b1,
    const float* __restrict__ w2, const float* __restrict__ b2,
    const float* __restrict__ fw1, const float* __restrict__ fb1,
    const float* __restrict__ fw2, const float* __restrict__ fb2,
    const float* __restrict__ mask, float* __restrict__ out) {
    const int b = blockIdx.x;
    const float m = mask[b];   // block-uniform
    if (m == 0.0f) {
        if (threadIdx.x == 0) { out[2 * b] = 0.f; out[2 * b + 1] = 0.f; }
        return;
    }

    __shared__ float h1p[C1][PH][CW + 2];      // pooled conv1 chunk + halo
    __shared__ float h2c[C2][P2H][CW / 2];     // pooled conv2 chunk
    __shared__ float y[NFC1];                  // fc1 accumulator
    __shared__ float w1s[C1][3][3];
    __shared__ float w2s[C2][C1][3][3];
    __shared__ float b1s[C1], b2s[C2];

    const float* xb = x + (size_t)b * (HH * WW);

    for (int i = threadIdx.x; i < C1 * 9; i += 256) ((float*)w1s)[i] = w1[i];
    for (int i = threadIdx.x; i < C2 * C1 * 9; i += 256) ((float*)w2s)[i] = w2[i];
    for (int i = threadIdx.x; i < C1; i += 256) b1s[i] = b1[i];
    for (int i = threadIdx.x; i < C2; i += 256) b2s[i] = b2[i];
    for (int i = threadIdx.x; i < NFC1; i += 256) y[i] = fb1[i];
    __syncthreads();

    for (int c0 = 0; c0 < PW; c0 += CW) {
        // -------- phase 1: conv1 + relu + pool into h1p (with 1-col halo) ----
        for (int i = threadIdx.x; i < C1 * PH * (CW + 2); i += 256) {
            const int lc = i % (CW + 2);
            const int r  = (i / (CW + 2)) % PH;
            const int ch = i / ((CW + 2) * PH);
            const int cc = c0 - 1 + lc;          // global pooled col
            float v = 0.f;                       // zero-pad outside [0,PW)
            if (cc >= 0 && cc < PW) {
                float mx = 0.f;                  // relu outputs are >= 0
                for (int pr = 0; pr < 2; ++pr) {
                    const int R = 2 * r + pr;    // conv1 out row 0..11
                    for (int pc = 0; pc < 2; ++pc) {
                        const int Cc = 2 * cc + pc;  // conv1 out col 0..1023
                        float acc = b1s[ch];
                        for (int dr = -1; dr <= 1; ++dr) {
                            const int rr = R + dr;
                            if (rr < 0 || rr >= HH) continue;
                            for (int dc = -1; dc <= 1; ++dc) {
                                const int cx = Cc + dc;
                                if (cx < 0 || cx >= WW) continue;
                                acc += xb[rr * WW + cx] * w1s[ch][dr + 1][dc + 1];
                            }
                        }
                        mx = fmaxf(mx, fmaxf(acc, 0.f));
                    }
                }
                v = mx;
            }
            h1p[ch][r][lc] = v;
        }
        __syncthreads();

        // -------- phase 2: conv2 + relu + pool into h2c ---------------------
        for (int i = threadIdx.x; i < C2 * P2H * (CW / 2); i += 256) {
            const int wl = i % (CW / 2);
            const int r2 = (i / (CW / 2)) % P2H;
            const int oc = i / ((CW / 2) * P2H);
            float mx = 0.f;
            for (int pr = 0; pr < 2; ++pr) {
                const int R = 2 * r2 + pr;       // conv2 out row 0..5
                for (int pc = 0; pc < 2; ++pc) {
                    const int Cl = 2 * wl + pc;  // local col within chunk
                    float acc = b2s[oc];
                    for (int ic = 0; ic < C1; ++ic) {
                        for (int dr = -1; dr <= 1; ++dr) {
                            const int rr = R + dr;
                            if (rr < 0 || rr >= PH) continue;
                            for (int dc = -1; dc <= 1; ++dc) {
                                // global col = c0 + Cl + dc -> local halo idx
                                acc += h1p[ic][rr][Cl + 1 + dc] *
                                       w2s[oc][ic][dr + 1][dc + 1];
                            }
                        }
                    }
                    mx = fmaxf(mx, fmaxf(acc, 0.f));
                }
            }
            h2c[oc][r2][wl] = mx;
        }
        __syncthreads();

        // -------- phase 3: fc1 partial over this chunk ----------------------
        if (threadIdx.x < NFC1) {
            const int o = threadIdx.x;
            const float* wrow = fw1 + (size_t)o * FLAT;
            float acc = 0.f;
            for (int oc = 0; oc < C2; ++oc)
                for (int r2 = 0; r2 < P2H; ++r2)
                    for (int wl = 0; wl < CW / 2; ++wl) {
                        const int wg = c0 / 2 + wl;  // global pooled-2 col
                        acc += h2c[oc][r2][wl] *
                               wrow[oc * (P2H * P2W) + r2 * P2W + wg];
                    }
            y[o] += acc;
        }
        __syncthreads();
    }

    // -------- fc2 + mask --------------------------------------------------
    if (threadIdx.x == 0) {
        float o0 = fb2[0], o1 = fb2[1];
        for (int o = 0; o < NFC1; ++o) {
            const float h = fmaxf(y[o], 0.f);
            o0 += h * fw2[o];            // fw2 is [2,128] row-major
            o1 += h * fw2[NFC1 + o];
        }
        out[2 * b]     = o0 * m;
        out[2 * b + 1] = o1 * m;
    }
}

extern "C" void kernel_launch(void* const* d_in, const int* in_sizes, int n_in,
                              void* d_out, int out_size, void* d_ws, size_t ws_size,
                              hipStream_t stream) {
    const float* x   = (const float*)d_in[0];
    const float* w1  = (const float*)d_in[1];
    const float* b1  = (const float*)d_in[2];
    const float* w2  = (const float*)d_in[3];
    const float* b2  = (const float*)d_in[4];
    const float* fw1 = (const float*)d_in[5];
    const float* fb1 = (const float*)d_in[6];
    const float* fw2 = (const float*)d_in[7];
    const float* fb2 = (const float*)d_in[8];
    float* out  = (float*)d_out;
    float* mask = (float*)d_ws;   // 256 floats of scratch

    entropy_kernel<<<BATCH, 256, 0, stream>>>(x, mask);
    cnn_kernel<<<BATCH, 256, 0, stream>>>(x, w1, b1, w2, b2,
                                          fw1, fb1, fw2, fb2, mask, out);
}

// Round 2
// 82.924 us; speedup vs baseline: 1.1831x; 1.1831x over previous
//
#include <hip/hip_runtime.h>
#include <math.h>

// Problem constants (match reference)
#define HH    13
#define WW    1024
#define BATCH 256
#define C1    16
#define C2    32
#define PH    6      // pooled h1 rows   (13 -> floor 6)
#define PW    512    // pooled h1 cols   (1024 -> 512)
#define P2H   3      // pooled h2 rows   (6 -> 3)
#define P2W   256    // pooled h2 cols   (512 -> 256)
#define FLAT  (C2 * P2H * P2W)   // 24576
#define NFC1  128
#define CW    64     // chunk width in pooled-h1 column space

// ---------------------------------------------------------------------------
// Fused kernel: per-sample entropy gate + (conditionally) the full network.
// Block b handles sample b.
//   ent = log(S) - T/S,  S = sum(a), T = sum(a*log a), a = |x|+1e-10
//   out[b] = mask * f(x_b); when mask==0 (provably, by computation), f is
//   skipped — exact algebraic short-circuit, data-dependent per call.
// ---------------------------------------------------------------------------
__global__ __launch_bounds__(256) void qualia_fused_kernel(
    const float* __restrict__ x,
    const float* __restrict__ w1, const float* __restrict__ b1,
    const float* __restrict__ w2, const float* __restrict__ b2,
    const float* __restrict__ fw1, const float* __restrict__ fb1,
    const float* __restrict__ fw2, const float* __restrict__ fb2,
    float* __restrict__ out) {
    const int b = blockIdx.x;
    const float* xb = x + (size_t)b * (HH * WW);

    // ---------------- entropy (vectorized float4, 13 iters exact) ----------
    float s = 0.f, t = 0.f;
    const float4* xv = (const float4*)xb;           // 13312/4 = 3328 = 256*13
    #pragma unroll
    for (int it = 0; it < 13; ++it) {
        const float4 v = xv[it * 256 + threadIdx.x];
        float a;
        a = fabsf(v.x) + 1e-10f; s += a; t += a * __logf(a);
        a = fabsf(v.y) + 1e-10f; s += a; t += a * __logf(a);
        a = fabsf(v.z) + 1e-10f; s += a; t += a * __logf(a);
        a = fabsf(v.w) + 1e-10f; s += a; t += a * __logf(a);
    }
    for (int off = 32; off >= 1; off >>= 1) {
        s += __shfl_down(s, off);
        t += __shfl_down(t, off);
    }
    __shared__ float ss[4], tt[4];
    __shared__ float m_sh;
    const int wave = threadIdx.x >> 6;
    const int lane = threadIdx.x & 63;
    if (lane == 0) { ss[wave] = s; tt[wave] = t; }
    __syncthreads();
    if (threadIdx.x == 0) {
        const float S = ss[0] + ss[1] + ss[2] + ss[3];
        const float T = tt[0] + tt[1] + tt[2] + tt[3];
        const float ent = __logf(S) - T / S;
        m_sh = (ent < 2.0f) ? 1.0f : 0.0f;
    }
    __syncthreads();
    const float m = m_sh;   // block-uniform

    if (m == 0.0f) {
        if (threadIdx.x == 0) { out[2 * b] = 0.f; out[2 * b + 1] = 0.f; }
        return;
    }

    // ---------------- full network path (exact, LDS-chunked) ---------------
    __shared__ float h1p[C1][PH][CW + 2];      // pooled conv1 chunk + halo
    __shared__ float h2c[C2][P2H][CW / 2];     // pooled conv2 chunk
    __shared__ float y[NFC1];                  // fc1 accumulator
    __shared__ float w1s[C1][3][3];
    __shared__ float w2s[C2][C1][3][3];
    __shared__ float b1s[C1], b2s[C2];

    for (int i = threadIdx.x; i < C1 * 9; i += 256) ((float*)w1s)[i] = w1[i];
    for (int i = threadIdx.x; i < C2 * C1 * 9; i += 256) ((float*)w2s)[i] = w2[i];
    for (int i = threadIdx.x; i < C1; i += 256) b1s[i] = b1[i];
    for (int i = threadIdx.x; i < C2; i += 256) b2s[i] = b2[i];
    for (int i = threadIdx.x; i < NFC1; i += 256) y[i] = fb1[i];
    __syncthreads();

    for (int c0 = 0; c0 < PW; c0 += CW) {
        // -------- phase 1: conv1 + relu + pool into h1p (with 1-col halo) ---
        for (int i = threadIdx.x; i < C1 * PH * (CW + 2); i += 256) {
            const int lc = i % (CW + 2);
            const int r  = (i / (CW + 2)) % PH;
            const int ch = i / ((CW + 2) * PH);
            const int cc = c0 - 1 + lc;          // global pooled col
            float v = 0.f;                       // zero-pad outside [0,PW)
            if (cc >= 0 && cc < PW) {
                float mx = 0.f;                  // relu outputs are >= 0
                for (int pr = 0; pr < 2; ++pr) {
                    const int R = 2 * r + pr;    // conv1 out row 0..11
                    for (int pc = 0; pc < 2; ++pc) {
                        const int Cc = 2 * cc + pc;  // conv1 out col 0..1023
                        float acc = b1s[ch];
                        for (int dr = -1; dr <= 1; ++dr) {
                            const int rr = R + dr;
                            if (rr < 0 || rr >= HH) continue;
                            for (int dc = -1; dc <= 1; ++dc) {
                                const int cx = Cc + dc;
                                if (cx < 0 || cx >= WW) continue;
                                acc += xb[rr * WW + cx] * w1s[ch][dr + 1][dc + 1];
                            }
                        }
                        mx = fmaxf(mx, fmaxf(acc, 0.f));
                    }
                }
                v = mx;
            }
            h1p[ch][r][lc] = v;
        }
        __syncthreads();

        // -------- phase 2: conv2 + relu + pool into h2c ---------------------
        for (int i = threadIdx.x; i < C2 * P2H * (CW / 2); i += 256) {
            const int wl = i % (CW / 2);
            const int r2 = (i / (CW / 2)) % P2H;
            const int oc = i / ((CW / 2) * P2H);
            float mx = 0.f;
            for (int pr = 0; pr < 2; ++pr) {
                const int R = 2 * r2 + pr;       // conv2 out row 0..5
                for (int pc = 0; pc < 2; ++pc) {
                    const int Cl = 2 * wl + pc;  // local col within chunk
                    float acc = b2s[oc];
                    for (int ic = 0; ic < C1; ++ic) {
                        for (int dr = -1; dr <= 1; ++dr) {
                            const int rr = R + dr;
                            if (rr < 0 || rr >= PH) continue;
                            for (int dc = -1; dc <= 1; ++dc) {
                                acc += h1p[ic][rr][Cl + 1 + dc] *
                                       w2s[oc][ic][dr + 1][dc + 1];
                            }
                        }
                    }
                    mx = fmaxf(mx, fmaxf(acc, 0.f));
                }
            }
            h2c[oc][r2][wl] = mx;
        }
        __syncthreads();

        // -------- phase 3: fc1 partial over this chunk ----------------------
        if (threadIdx.x < NFC1) {
            const int o = threadIdx.x;
            const float* wrow = fw1 + (size_t)o * FLAT;
            float acc = 0.f;
            for (int oc = 0; oc < C2; ++oc)
                for (int r2 = 0; r2 < P2H; ++r2)
                    for (int wl = 0; wl < CW / 2; ++wl) {
                        const int wg = c0 / 2 + wl;  // global pooled-2 col
                        acc += h2c[oc][r2][wl] *
                               wrow[oc * (P2H * P2W) + r2 * P2W + wg];
                    }
            y[o] += acc;
        }
        __syncthreads();
    }

    // -------- fc2 + mask ---------------------------------------------------
    if (threadIdx.x == 0) {
        float o0 = fb2[0], o1 = fb2[1];
        for (int o = 0; o < NFC1; ++o) {
            const float h = fmaxf(y[o], 0.f);
            o0 += h * fw2[o];            // fw2 is [2,128] row-major
            o1 += h * fw2[NFC1 + o];
        }
        out[2 * b]     = o0 * m;
        out[2 * b + 1] = o1 * m;
    }
}

extern "C" void kernel_launch(void* const* d_in, const int* in_sizes, int n_in,
                              void* d_out, int out_size, void* d_ws, size_t ws_size,
                              hipStream_t stream) {
    const float* x   = (const float*)d_in[0];
    const float* w1  = (const float*)d_in[1];
    const float* b1  = (const float*)d_in[2];
    const float* w2  = (const float*)d_in[3];
    const float* b2  = (const float*)d_in[4];
    const float* fw1 = (const float*)d_in[5];
    const float* fb1 = (const float*)d_in[6];
    const float* fw2 = (const float*)d_in[7];
    const float* fb2 = (const float*)d_in[8];
    float* out = (float*)d_out;

    qualia_fused_kernel<<<BATCH, 256, 0, stream>>>(x, w1, b1, w2, b2,
                                                   fw1, fb1, fw2, fb2, out);
}